// Round 10
// baseline (261.324 us; speedup 1.0000x reference)
//
#include <hip/hip_runtime.h>
#include <hip/hip_bf16.h>

#define RESV 32
#define R3V (RESV * RESV * RESV)
#define R3P1 (R3V + 1)
#define CH 128  // sorted points per wave-chunk in k_gather4

__device__ __forceinline__ unsigned short f2bf(float f) {
    __hip_bfloat16 h = __float2bfloat16(f);  // RNE
    unsigned short u;
    __builtin_memcpy(&u, &h, 2);
    return u;
}
__device__ __forceinline__ unsigned int pkbf(float lo, float hi) {
    return (unsigned int)f2bf(lo) | ((unsigned int)f2bf(hi) << 16);
}
__device__ __forceinline__ float blo(unsigned int u) { return __uint_as_float(u << 16); }
__device__ __forceinline__ float bhi(unsigned int u) { return __uint_as_float(u & 0xffff0000u); }

// ws header (floats): [0, 96B) per-batch sum partials part[b*96 + x*3 + d]
//                     [768, +32B) per-batch max partials maxp[b*32 + x]
// header total = 1024 floats; counts follow.

// ---- K1: per-batch per-block coordinate sums -> partials (no atomics) ----
// Also zeroes the counts array (stream-ordered before k_points; distinct buffer).
__global__ void k_sums(const float* __restrict__ coords, float* __restrict__ part,
                       int4* __restrict__ counts4, int N) {
    const int b = blockIdx.y;
    // fold counts zeroing: 256 blocks x 256 threads x int4 == B*R3V ints (B=8)
    {
        const int g = (blockIdx.y * gridDim.x + blockIdx.x) * blockDim.x + threadIdx.x;
        counts4[g] = make_int4(0, 0, 0, 0);
    }
    const float* cb = coords + (size_t)b * 3 * N;
    float sx = 0.f, sy = 0.f, sz = 0.f;
    for (int n = blockIdx.x * blockDim.x + threadIdx.x; n < N; n += gridDim.x * blockDim.x) {
        sx += cb[n];
        sy += cb[N + n];
        sz += cb[2 * N + n];
    }
    for (int off = 32; off > 0; off >>= 1) {
        sx += __shfl_down(sx, off);
        sy += __shfl_down(sy, off);
        sz += __shfl_down(sz, off);
    }
    __shared__ float red[3][4];
    const int lane = threadIdx.x & 63;
    const int wv   = threadIdx.x >> 6;
    if (lane == 0) { red[0][wv] = sx; red[1][wv] = sy; red[2][wv] = sz; }
    __syncthreads();
    if (threadIdx.x == 0) {
        float tx = 0.f, ty = 0.f, tz = 0.f;
        const int nw = blockDim.x >> 6;
        for (int w = 0; w < nw; ++w) { tx += red[0][w]; ty += red[1][w]; tz += red[2][w]; }
        float* p = part + (b * 32 + blockIdx.x) * 3;
        p[0] = tx; p[1] = ty; p[2] = tz;
    }
}

// ---- K2: per-batch per-block max radius -> partials (no atomics) ----
__global__ void k_maxrad(const float* __restrict__ coords, const float* __restrict__ part,
                         float* __restrict__ maxp, int N) {
    const int b = blockIdx.y;
    __shared__ float sp[96];
    if (threadIdx.x < 96) sp[threadIdx.x] = part[b * 96 + threadIdx.x];
    __syncthreads();
    const float invN = 1.0f / (float)N;
    float mx = 0.f, my = 0.f, mz = 0.f;
    for (int x = 0; x < 32; ++x) { mx += sp[x * 3]; my += sp[x * 3 + 1]; mz += sp[x * 3 + 2]; }
    mx *= invN; my *= invN; mz *= invN;

    const float* cb = coords + (size_t)b * 3 * N;
    float r = 0.f;
    for (int n = blockIdx.x * blockDim.x + threadIdx.x; n < N; n += gridDim.x * blockDim.x) {
        const float dx = cb[n] - mx;
        const float dy = cb[N + n] - my;
        const float dz = cb[2 * N + n] - mz;
        r = fmaxf(r, sqrtf(dx * dx + dy * dy + dz * dz));
    }
    for (int off = 32; off > 0; off >>= 1) r = fmaxf(r, __shfl_down(r, off));
    __shared__ float red[4];
    const int lane = threadIdx.x & 63;
    const int wv   = threadIdx.x >> 6;
    if (lane == 0) red[wv] = r;
    __syncthreads();
    if (threadIdx.x == 0) {
        const int nw = blockDim.x >> 6;
        float t = 0.f;
        for (int w = 0; w < nw; ++w) t = fmaxf(t, red[w]);
        maxp[b * 32 + blockIdx.x] = t;
    }
}

// ---- K3: norm coords + packed (voxel idx, rank); counts via atomic return ----
__global__ void k_points(const float* __restrict__ coords, const float* __restrict__ part,
                         const float* __restrict__ maxp,
                         float* __restrict__ norm_out, unsigned int* __restrict__ pk,
                         int* __restrict__ counts, int N) {
    const int b = blockIdx.y;
    __shared__ float sp[96];
    __shared__ float mp[32];
    if (threadIdx.x < 96) sp[threadIdx.x] = part[b * 96 + threadIdx.x];
    if (threadIdx.x < 32) mp[threadIdx.x] = maxp[b * 32 + threadIdx.x];
    __syncthreads();
    const float invN = 1.0f / (float)N;
    float mean[3] = {0.f, 0.f, 0.f};
    float mrad = 0.f;
    for (int x = 0; x < 32; ++x) {
        mean[0] += sp[x * 3]; mean[1] += sp[x * 3 + 1]; mean[2] += sp[x * 3 + 2];
        mrad = fmaxf(mrad, mp[x]);
    }
    const float scale = 2.0f * mrad;

    const int n = blockIdx.x * blockDim.x + threadIdx.x;
    if (n >= N) return;
    const float* cb = coords + (size_t)b * 3 * N;
    float* nb = norm_out + (size_t)b * 3 * N;

    int flat = 0;
#pragma unroll
    for (int d = 0; d < 3; ++d) {
        float nc = (cb[d * N + n] - mean[d] * invN) / scale + 0.5f;
        nc = fminf(fmaxf(nc * (float)RESV, 0.0f), (float)(RESV - 1));
        nb[d * N + n] = nc;
        flat = flat * RESV + (int)rintf(nc);
    }
    const int jl = atomicAdd(&counts[b * R3V + flat], 1);
    pk[(size_t)b * N + n] = ((unsigned int)flat << 17) | (unsigned int)jl;
}

// ---- K4: per-batch exclusive scan of counts -> start (stride R3P1, sentinel) ----
__global__ __launch_bounds__(1024, 1) void k_scan(const int* __restrict__ counts,
                                                  int* __restrict__ start, int N) {
    const int b = blockIdx.x;
    const int t = threadIdx.x;
    const int base  = b * R3V + t * 32;
    const int baseS = b * R3P1 + t * 32;
    int c[32];
    int T = 0;
#pragma unroll
    for (int i = 0; i < 32; ++i) { c[i] = counts[base + i]; T += c[i]; }
    int incl = T;
    const int lane = t & 63;
    for (int off = 1; off < 64; off <<= 1) {
        int y = __shfl_up(incl, off);
        if (lane >= off) incl += y;
    }
    __shared__ int wsum[16];
    __shared__ int wbase[16];
    const int w = t >> 6;
    if (lane == 63) wsum[w] = incl;
    __syncthreads();
    if (t == 0) {
        int run = 0;
        for (int i = 0; i < 16; ++i) { wbase[i] = run; run += wsum[i]; }
    }
    __syncthreads();
    int run = wbase[w] + incl - T;  // exclusive prefix
#pragma unroll
    for (int i = 0; i < 32; ++i) {
        start[baseS + i] = run;
        run += c[i];
    }
    if (t == 1023) start[b * R3P1 + R3V] = run;  // == N
}

// ---- K5: feats [B,64,N] fp32 -> fTs [B,N,64] bf16, rows in sorted order ----
// 1D grid, b = bid % B so batch == XCD (write-locality via per-XCD L2).
__global__ __launch_bounds__(1024, 2) void k_transpose_perm(
        const float* __restrict__ feats, const unsigned int* __restrict__ pk,
        const int* __restrict__ startv,
        unsigned int* __restrict__ fTs32, int* __restrict__ voxid, int N, int B) {
    __shared__ unsigned short tile[256][66];
    __shared__ int jrow[256];
    const int bid = blockIdx.x;
    const int b   = bid % B;
    const int n0  = (bid / B) * 256;
    const int t   = threadIdx.x;
    const float* fb = feats + (size_t)b * 64 * N;

    const int c = t >> 4;
    const int q = t & 15;
    if (n0 + 256 <= N) {
#pragma unroll
        for (int i = 0; i < 4; ++i) {
            const int nn = q * 4 + i * 64;
            const float4 f = *(const float4*)(fb + (size_t)c * N + n0 + nn);
            tile[nn + 0][c] = f2bf(f.x);
            tile[nn + 1][c] = f2bf(f.y);
            tile[nn + 2][c] = f2bf(f.z);
            tile[nn + 3][c] = f2bf(f.w);
        }
    } else {
        for (int i = 0; i < 4; ++i) {
            const int nn = q * 4 + i * 64;
            for (int u = 0; u < 4; ++u) {
                const int n = n0 + nn + u;
                tile[nn + u][c] = f2bf((n < N) ? fb[(size_t)c * N + n] : 0.f);
            }
        }
    }
    if (t < 256) {
        const int n = n0 + t;
        if (n < N) {
            const unsigned int p = pk[(size_t)b * N + n];
            const int v  = (int)(p >> 17);
            const int j  = startv[(size_t)b * R3P1 + v] + (int)(p & 0x1FFFFu);
            jrow[t] = j;
            voxid[(size_t)b * N + j] = v;
        }
    }
    __syncthreads();

    const int wv   = t >> 6;
    const int lane = t & 63;
    const int lc   = lane & 31;
    const int ph   = lane >> 5;
    unsigned int* fo = fTs32 + (size_t)b * N * 32;
#pragma unroll
    for (int k = 0; k < 8; ++k) {
        const int p = k * 32 + wv * 2 + ph;
        if (n0 + p < N) {
            const unsigned int d = *(const unsigned int*)&tile[p][2 * lc];
            fo[(size_t)jrow[p] * 32 + lc] = d;
        }
    }
}

// ---- K6: atomic-free segmented reduction over sorted rows ----
// 1D grid, b = bid % B (batch == XCD). Chunk owns segments STARTING inside it.
__global__ __launch_bounds__(256) void k_gather4(const unsigned int* __restrict__ fTs32,
                                                 const int* __restrict__ voxid,
                                                 const int* __restrict__ startv,
                                                 unsigned int* __restrict__ gridT2,
                                                 int N, int nchunk, int B) {
    const int bid   = blockIdx.x;
    const int b     = bid % B;
    const int w     = threadIdx.x >> 6;
    const int lane  = threadIdx.x & 63;
    const int p     = lane >> 4;   // row parity 0..3
    const int lc    = lane & 15;   // channel quad
    const int chunk = (bid / B) * 4 + w;
    if (chunk >= nchunk) return;
    const int c0   = chunk * CH;
    const int end0 = min(c0 + CH, N);
    const uint2* fb = (const uint2*)(fTs32 + (size_t)b * N * 32);
    const int* vi = voxid  + (size_t)b * N;
    const int* sv = startv + (size_t)b * R3P1;
    uint2* gT = (uint2*)(gridT2) + (size_t)b * R3V * 16;

    int j;
    {
        const int v = vi[c0];
        const int s = sv[v];
        j = (s < c0) ? sv[v + 1] : s;
    }
    while (j < end0) {
        const int v = vi[j];           // wave-uniform
        const int e = sv[v + 1];
        float a0 = 0.f, a1 = 0.f, a2 = 0.f, a3 = 0.f;
        int r = j + p;
        for (; r + 12 < e; r += 16) {  // 4 uint2 loads in flight per lane
            const uint2 u0 = fb[(size_t)(r + 0) * 16 + lc];
            const uint2 u1 = fb[(size_t)(r + 4) * 16 + lc];
            const uint2 u2 = fb[(size_t)(r + 8) * 16 + lc];
            const uint2 u3 = fb[(size_t)(r + 12) * 16 + lc];
            a0 += (blo(u0.x) + blo(u1.x)) + (blo(u2.x) + blo(u3.x));
            a1 += (bhi(u0.x) + bhi(u1.x)) + (bhi(u2.x) + bhi(u3.x));
            a2 += (blo(u0.y) + blo(u1.y)) + (blo(u2.y) + blo(u3.y));
            a3 += (bhi(u0.y) + bhi(u1.y)) + (bhi(u2.y) + bhi(u3.y));
        }
        for (; r < e; r += 4) {
            const uint2 u = fb[(size_t)r * 16 + lc];
            a0 += blo(u.x);
            a1 += bhi(u.x);
            a2 += blo(u.y);
            a3 += bhi(u.y);
        }
        a0 += __shfl_xor(a0, 16); a0 += __shfl_xor(a0, 32);
        a1 += __shfl_xor(a1, 16); a1 += __shfl_xor(a1, 32);
        a2 += __shfl_xor(a2, 16); a2 += __shfl_xor(a2, 32);
        a3 += __shfl_xor(a3, 16); a3 += __shfl_xor(a3, 32);
        if (p == 0) {
            gT[(size_t)v * 16 + lc] = make_uint2(pkbf(a0, a1), pkbf(a2, a3));
        }
        j = e;
    }
}

// ---- K7: gridT bf16 [B,R3,64] -> grid fp32 [B,64,R3], /cnt, cnt==0 -> 0 ----
__global__ __launch_bounds__(256) void k_fin(const unsigned int* __restrict__ gridT2,
                                             const int* __restrict__ counts,
                                             float* __restrict__ grid) {
    __shared__ float tile[64][65];
    const int b    = blockIdx.y;
    const int v0   = blockIdx.x * 64;
    const int t    = threadIdx.x;
    const int lane = t & 63;
    const int w    = t >> 6;
    const unsigned int* g = gridT2 + ((size_t)b * R3V + v0) * 32;
#pragma unroll
    for (int k = 0; k < 8; ++k) {
        const int i  = t + k * 256;  // v*32 + cd
        const int v  = i >> 5;
        const int cd = i & 31;
        const unsigned int u = g[i];
        tile[v][2 * cd]     = blo(u);
        tile[v][2 * cd + 1] = bhi(u);
    }
    __syncthreads();
    const int cnt  = counts[(size_t)b * R3V + v0 + lane];
    const float rc = 1.0f / fmaxf((float)cnt, 1.0f);
    const bool occ = cnt > 0;
    float* gb = grid + (size_t)b * 64 * R3V;
#pragma unroll
    for (int k = 0; k < 16; ++k) {
        const int c = w + k * 4;
        gb[(size_t)c * R3V + v0 + lane] = occ ? tile[lane][c] * rc : 0.0f;
    }
}

// ============================ fallback: LDS-atomic scatter ============================

__device__ __forceinline__ int swz(int v) {
    return v ^ ((v >> 5) & 31) ^ ((v >> 10) & 31);
}

__global__ void k_recip_fb(const int* __restrict__ cnt, float* __restrict__ recip, int total) {
    const int i = blockIdx.x * blockDim.x + threadIdx.x;
    if (i < total) recip[i] = 1.0f / fmaxf((float)cnt[i], 1.0f);
}

__global__ __launch_bounds__(1024, 1) void k_scatter_lds(
        const float* __restrict__ feats, const unsigned int* __restrict__ pk,
        const float* __restrict__ recip, float* __restrict__ grid, int N, int C) {
    extern __shared__ float acc[];
    const int bc  = blockIdx.x;
    const int b   = bc / C;
    const int tid = threadIdx.x;
    for (int i = tid * 4; i < R3V; i += blockDim.x * 4)
        *(float4*)(acc + i) = make_float4(0.f, 0.f, 0.f, 0.f);
    __syncthreads();
    const float* fb = feats + (size_t)bc * N;
    const unsigned int* ib = pk + (size_t)b * N;
    for (int n = tid; n < N; n += blockDim.x) atomicAdd(&acc[swz((int)(ib[n] >> 17))], fb[n]);
    __syncthreads();
    const float* rb = recip + (size_t)b * R3V;
    float*       gb = grid  + (size_t)bc * R3V;
    for (int i = tid; i < R3V; i += blockDim.x)
        gb[i] = acc[swz(i)] * rb[i];
}

// ============================ launch ============================

extern "C" void kernel_launch(void* const* d_in, const int* in_sizes, int n_in,
                              void* d_out, int out_size, void* d_ws, size_t ws_size,
                              hipStream_t stream) {
    const float* feats  = (const float*)d_in[0];
    const float* coords = (const float*)d_in[1];

    const long long s0 = in_sizes[0], s1 = in_sizes[1];
    const int BC = (int)(((long long)out_size - s1) / R3V);  // B*C
    const int N  = (int)(s0 / BC);
    const int B  = (int)(s1 / (3LL * N));
    const int C  = BC / B;

    float* out_grid = (float*)d_out;               // [B, C, R3]
    float* out_norm = out_grid + (size_t)BC * R3V; // [B, 3, N]

    // ws layout (float32 slots). Header = 1024 floats (sum partials + max partials).
    const size_t BR3 = (size_t)B * R3V;
    const size_t BN  = (size_t)B * N;
    const size_t o_counts = 1024;
    const size_t o_start  = o_counts + BR3;
    const size_t o_recip  = o_start + (size_t)B * R3P1;  // fallback only
    const size_t o_pk     = o_recip + BR3;
    const size_t o_voxid  = o_pk + BN;
    size_t o_gridT = (o_voxid + BN + 63) & ~(size_t)63;        // bf16: BR3*32 slots
    size_t o_fTs   = (o_gridT + BR3 * 32 + 63) & ~(size_t)63;  // bf16: BN*32 slots
    const size_t need = (o_fTs + BN * 32) * sizeof(float);

    float*        ws_part = (float*)d_ws;                  // [B*32*3]
    float*        ws_maxp = (float*)d_ws + 768;            // [B*32]
    int*          counts  = (int*)d_ws + o_counts;
    int*          startv  = (int*)d_ws + o_start;
    float*        recip   = (float*)d_ws + o_recip;
    unsigned int* pk      = (unsigned int*)d_ws + o_pk;
    int*          voxid   = (int*)d_ws + o_voxid;
    unsigned int* gridT2  = (unsigned int*)((float*)d_ws + o_gridT);
    unsigned int* fTs32   = (unsigned int*)((float*)d_ws + o_fTs);

    const int BLK = 256;
    dim3 gRed(32, B);
    // k_sums also zeroes counts (B*R3V ints == gRed blocks * 256 threads * int4)
    k_sums<<<gRed, BLK, 0, stream>>>(coords, ws_part, (int4*)counts, N);
    k_maxrad<<<gRed, BLK, 0, stream>>>(coords, ws_part, ws_maxp, N);

    dim3 gPts((N + BLK - 1) / BLK, B);
    k_points<<<gPts, BLK, 0, stream>>>(coords, ws_part, ws_maxp, out_norm, pk, counts, N);

    if (ws_size >= need && C == 64) {
        k_scan<<<dim3(B), 1024, 0, stream>>>(counts, startv, N);
        const int nTB = (N + 255) / 256;
        k_transpose_perm<<<dim3(nTB * B), 1024, 0, stream>>>(feats, pk, startv,
                                                             fTs32, voxid, N, B);
        const int nchunk = (N + CH - 1) / CH;
        const int nGB = (nchunk + 3) / 4;
        k_gather4<<<dim3(nGB * B), 256, 0, stream>>>(fTs32, voxid, startv, gridT2,
                                                     N, nchunk, B);
        dim3 gF(R3V / 64, B);
        k_fin<<<gF, 256, 0, stream>>>(gridT2, counts, out_grid);
    } else {
        const int tot = B * R3V;
        k_recip_fb<<<(tot + BLK - 1) / BLK, BLK, 0, stream>>>(counts, recip, tot);
        k_scatter_lds<<<dim3(BC), 1024, R3V * sizeof(float), stream>>>(
            feats, pk, recip, out_grid, N, C);
    }
}

// Round 11
// 223.814 us; speedup vs baseline: 1.1676x; 1.1676x over previous
//
#include <hip/hip_runtime.h>
#include <hip/hip_bf16.h>

#define RESV 32
#define R3V (RESV * RESV * RESV)
#define R3P1 (R3V + 1)
#define CH 64  // sorted points per wave-chunk in k_gather4 (R6-proven)

__device__ __forceinline__ unsigned short f2bf(float f) {
    __hip_bfloat16 h = __float2bfloat16(f);  // RNE
    unsigned short u;
    __builtin_memcpy(&u, &h, 2);
    return u;
}
__device__ __forceinline__ unsigned int pkbf(float lo, float hi) {
    return (unsigned int)f2bf(lo) | ((unsigned int)f2bf(hi) << 16);
}
__device__ __forceinline__ float blo(unsigned int u) { return __uint_as_float(u << 16); }
__device__ __forceinline__ float bhi(unsigned int u) { return __uint_as_float(u & 0xffff0000u); }

// ws header (floats): [0, 768) per-batch sum partials part[b*96 + x*3 + d]
//                     [768, 1024) per-batch max partials maxp[b*32 + x]

// ---- K1: per-batch per-block coordinate sums -> partials (no atomics) ----
// Also zeroes counts (stream-ordered before k_points; distinct buffer;
// 256 blocks x 256 threads x int4 == B*R3V ints for B=8).
__global__ void k_sums(const float* __restrict__ coords, float* __restrict__ part,
                       int4* __restrict__ counts4, int N) {
    const int b = blockIdx.y;
    {
        const int g = (blockIdx.y * gridDim.x + blockIdx.x) * blockDim.x + threadIdx.x;
        counts4[g] = make_int4(0, 0, 0, 0);
    }
    const float* cb = coords + (size_t)b * 3 * N;
    float sx = 0.f, sy = 0.f, sz = 0.f;
    for (int n = blockIdx.x * blockDim.x + threadIdx.x; n < N; n += gridDim.x * blockDim.x) {
        sx += cb[n];
        sy += cb[N + n];
        sz += cb[2 * N + n];
    }
    for (int off = 32; off > 0; off >>= 1) {
        sx += __shfl_down(sx, off);
        sy += __shfl_down(sy, off);
        sz += __shfl_down(sz, off);
    }
    __shared__ float red[3][4];
    const int lane = threadIdx.x & 63;
    const int wv   = threadIdx.x >> 6;
    if (lane == 0) { red[0][wv] = sx; red[1][wv] = sy; red[2][wv] = sz; }
    __syncthreads();
    if (threadIdx.x == 0) {
        float tx = 0.f, ty = 0.f, tz = 0.f;
        const int nw = blockDim.x >> 6;
        for (int w = 0; w < nw; ++w) { tx += red[0][w]; ty += red[1][w]; tz += red[2][w]; }
        float* p = part + (b * 32 + blockIdx.x) * 3;
        p[0] = tx; p[1] = ty; p[2] = tz;
    }
}

// ---- K2: per-batch per-block max radius -> partials (no atomics) ----
__global__ void k_maxrad(const float* __restrict__ coords, const float* __restrict__ part,
                         float* __restrict__ maxp, int N) {
    const int b = blockIdx.y;
    __shared__ float sp[96];
    if (threadIdx.x < 96) sp[threadIdx.x] = part[b * 96 + threadIdx.x];
    __syncthreads();
    const float invN = 1.0f / (float)N;
    float mx = 0.f, my = 0.f, mz = 0.f;
    for (int x = 0; x < 32; ++x) { mx += sp[x * 3]; my += sp[x * 3 + 1]; mz += sp[x * 3 + 2]; }
    mx *= invN; my *= invN; mz *= invN;

    const float* cb = coords + (size_t)b * 3 * N;
    float r = 0.f;
    for (int n = blockIdx.x * blockDim.x + threadIdx.x; n < N; n += gridDim.x * blockDim.x) {
        const float dx = cb[n] - mx;
        const float dy = cb[N + n] - my;
        const float dz = cb[2 * N + n] - mz;
        r = fmaxf(r, sqrtf(dx * dx + dy * dy + dz * dz));
    }
    for (int off = 32; off > 0; off >>= 1) r = fmaxf(r, __shfl_down(r, off));
    __shared__ float red[4];
    const int lane = threadIdx.x & 63;
    const int wv   = threadIdx.x >> 6;
    if (lane == 0) red[wv] = r;
    __syncthreads();
    if (threadIdx.x == 0) {
        const int nw = blockDim.x >> 6;
        float t = 0.f;
        for (int w = 0; w < nw; ++w) t = fmaxf(t, red[w]);
        maxp[b * 32 + blockIdx.x] = t;
    }
}

// ---- K3: norm coords + packed (voxel idx << 17 | rank); counts via atomic return ----
__global__ void k_points(const float* __restrict__ coords, const float* __restrict__ part,
                         const float* __restrict__ maxp,
                         float* __restrict__ norm_out, unsigned int* __restrict__ pk,
                         int* __restrict__ counts, int N) {
    const int b = blockIdx.y;
    __shared__ float sp[96];
    __shared__ float mp[32];
    if (threadIdx.x < 96) sp[threadIdx.x] = part[b * 96 + threadIdx.x];
    if (threadIdx.x < 32) mp[threadIdx.x] = maxp[b * 32 + threadIdx.x];
    __syncthreads();
    const float invN = 1.0f / (float)N;
    float mean[3] = {0.f, 0.f, 0.f};
    float mrad = 0.f;
    for (int x = 0; x < 32; ++x) {
        mean[0] += sp[x * 3]; mean[1] += sp[x * 3 + 1]; mean[2] += sp[x * 3 + 2];
        mrad = fmaxf(mrad, mp[x]);
    }
    const float scale = 2.0f * mrad;

    const int n = blockIdx.x * blockDim.x + threadIdx.x;
    if (n >= N) return;
    const float* cb = coords + (size_t)b * 3 * N;
    float* nb = norm_out + (size_t)b * 3 * N;

    int flat = 0;
#pragma unroll
    for (int d = 0; d < 3; ++d) {
        float nc = (cb[d * N + n] - mean[d] * invN) / scale + 0.5f;
        nc = fminf(fmaxf(nc * (float)RESV, 0.0f), (float)(RESV - 1));
        nb[d * N + n] = nc;
        flat = flat * RESV + (int)rintf(nc);
    }
    const int jl = atomicAdd(&counts[b * R3V + flat], 1);
    pk[(size_t)b * N + n] = ((unsigned int)flat << 17) | (unsigned int)jl;
}

// ---- K4: per-batch exclusive scan of counts -> start (stride R3P1, sentinel) ----
__global__ __launch_bounds__(1024, 1) void k_scan(const int* __restrict__ counts,
                                                  int* __restrict__ start, int N) {
    const int b = blockIdx.x;
    const int t = threadIdx.x;
    const int base  = b * R3V + t * 32;
    const int baseS = b * R3P1 + t * 32;
    int c[32];
    int T = 0;
#pragma unroll
    for (int i = 0; i < 32; ++i) { c[i] = counts[base + i]; T += c[i]; }
    int incl = T;
    const int lane = t & 63;
    for (int off = 1; off < 64; off <<= 1) {
        int y = __shfl_up(incl, off);
        if (lane >= off) incl += y;
    }
    __shared__ int wsum[16];
    __shared__ int wbase[16];
    const int w = t >> 6;
    if (lane == 63) wsum[w] = incl;
    __syncthreads();
    if (t == 0) {
        int run = 0;
        for (int i = 0; i < 16; ++i) { wbase[i] = run; run += wsum[i]; }
    }
    __syncthreads();
    int run = wbase[w] + incl - T;  // exclusive prefix
#pragma unroll
    for (int i = 0; i < 32; ++i) {
        start[baseS + i] = run;
        run += c[i];
    }
    if (t == 1023) start[b * R3P1 + R3V] = run;  // == N
}

// ---- K5: feats [B,64,N] fp32 -> fTs [B,N,64] bf16, rows in sorted order ----
// 2D grid (x = n-tile, y = batch): consecutive dispatches share a batch (L2 read adjacency).
__global__ __launch_bounds__(1024, 2) void k_transpose_perm(
        const float* __restrict__ feats, const unsigned int* __restrict__ pk,
        const int* __restrict__ startv,
        unsigned int* __restrict__ fTs32, int* __restrict__ voxid, int N) {
    __shared__ unsigned short tile[256][66];
    __shared__ int jrow[256];
    const int b  = blockIdx.y;
    const int n0 = blockIdx.x * 256;
    const int t  = threadIdx.x;
    const float* fb = feats + (size_t)b * 64 * N;

    const int c = t >> 4;
    const int q = t & 15;
    if (n0 + 256 <= N) {
#pragma unroll
        for (int i = 0; i < 4; ++i) {
            const int nn = q * 4 + i * 64;
            const float4 f = *(const float4*)(fb + (size_t)c * N + n0 + nn);
            tile[nn + 0][c] = f2bf(f.x);
            tile[nn + 1][c] = f2bf(f.y);
            tile[nn + 2][c] = f2bf(f.z);
            tile[nn + 3][c] = f2bf(f.w);
        }
    } else {
        for (int i = 0; i < 4; ++i) {
            const int nn = q * 4 + i * 64;
            for (int u = 0; u < 4; ++u) {
                const int n = n0 + nn + u;
                tile[nn + u][c] = f2bf((n < N) ? fb[(size_t)c * N + n] : 0.f);
            }
        }
    }
    if (t < 256) {
        const int n = n0 + t;
        if (n < N) {
            const unsigned int p = pk[(size_t)b * N + n];
            const int v = (int)(p >> 17);
            const int j = startv[(size_t)b * R3P1 + v] + (int)(p & 0x1FFFFu);
            jrow[t] = j;
            voxid[(size_t)b * N + j] = v;
        }
    }
    __syncthreads();

    const int wv   = t >> 6;
    const int lane = t & 63;
    const int lc   = lane & 31;
    const int ph   = lane >> 5;
    unsigned int* fo = fTs32 + (size_t)b * N * 32;
#pragma unroll
    for (int k = 0; k < 8; ++k) {
        const int p = k * 32 + wv * 2 + ph;
        if (n0 + p < N) {
            const unsigned int d = *(const unsigned int*)&tile[p][2 * lc];
            fo[(size_t)jrow[p] * 32 + lc] = d;
        }
    }
}

// ---- K6: atomic-free segmented reduction over sorted rows (2D grid) ----
__global__ __launch_bounds__(256) void k_gather4(const unsigned int* __restrict__ fTs32,
                                                 const int* __restrict__ voxid,
                                                 const int* __restrict__ startv,
                                                 unsigned int* __restrict__ gridT2,
                                                 int N, int nchunk) {
    const int w     = threadIdx.x >> 6;
    const int lane  = threadIdx.x & 63;
    const int p     = lane >> 4;   // row parity 0..3
    const int lc    = lane & 15;   // channel quad
    const int chunk = blockIdx.x * 4 + w;
    if (chunk >= nchunk) return;
    const int b    = blockIdx.y;
    const int c0   = chunk * CH;
    const int end0 = min(c0 + CH, N);
    const uint2* fb = (const uint2*)(fTs32 + (size_t)b * N * 32);
    const int* vi = voxid  + (size_t)b * N;
    const int* sv = startv + (size_t)b * R3P1;
    uint2* gT = (uint2*)(gridT2) + (size_t)b * R3V * 16;

    int j;
    {
        const int v = vi[c0];
        const int s = sv[v];
        j = (s < c0) ? sv[v + 1] : s;
    }
    while (j < end0) {
        const int v = vi[j];           // wave-uniform
        const int e = sv[v + 1];
        float a0 = 0.f, a1 = 0.f, a2 = 0.f, a3 = 0.f;
        int r = j + p;
        for (; r + 12 < e; r += 16) {  // 4 uint2 loads in flight per lane
            const uint2 u0 = fb[(size_t)(r + 0) * 16 + lc];
            const uint2 u1 = fb[(size_t)(r + 4) * 16 + lc];
            const uint2 u2 = fb[(size_t)(r + 8) * 16 + lc];
            const uint2 u3 = fb[(size_t)(r + 12) * 16 + lc];
            a0 += (blo(u0.x) + blo(u1.x)) + (blo(u2.x) + blo(u3.x));
            a1 += (bhi(u0.x) + bhi(u1.x)) + (bhi(u2.x) + bhi(u3.x));
            a2 += (blo(u0.y) + blo(u1.y)) + (blo(u2.y) + blo(u3.y));
            a3 += (bhi(u0.y) + bhi(u1.y)) + (bhi(u2.y) + bhi(u3.y));
        }
        for (; r < e; r += 4) {
            const uint2 u = fb[(size_t)r * 16 + lc];
            a0 += blo(u.x);
            a1 += bhi(u.x);
            a2 += blo(u.y);
            a3 += bhi(u.y);
        }
        a0 += __shfl_xor(a0, 16); a0 += __shfl_xor(a0, 32);
        a1 += __shfl_xor(a1, 16); a1 += __shfl_xor(a1, 32);
        a2 += __shfl_xor(a2, 16); a2 += __shfl_xor(a2, 32);
        a3 += __shfl_xor(a3, 16); a3 += __shfl_xor(a3, 32);
        if (p == 0) {
            gT[(size_t)v * 16 + lc] = make_uint2(pkbf(a0, a1), pkbf(a2, a3));
        }
        j = e;
    }
}

// ---- K7: gridT bf16 [B,R3,64] -> grid fp32 [B,64,R3], /cnt, cnt==0 -> 0 ----
__global__ __launch_bounds__(256) void k_fin(const unsigned int* __restrict__ gridT2,
                                             const int* __restrict__ counts,
                                             float* __restrict__ grid) {
    __shared__ float tile[64][65];
    const int b    = blockIdx.y;
    const int v0   = blockIdx.x * 64;
    const int t    = threadIdx.x;
    const int lane = t & 63;
    const int w    = t >> 6;
    const unsigned int* g = gridT2 + ((size_t)b * R3V + v0) * 32;
#pragma unroll
    for (int k = 0; k < 8; ++k) {
        const int i  = t + k * 256;  // v*32 + cd
        const int v  = i >> 5;
        const int cd = i & 31;
        const unsigned int u = g[i];
        tile[v][2 * cd]     = blo(u);
        tile[v][2 * cd + 1] = bhi(u);
    }
    __syncthreads();
    const int cnt  = counts[(size_t)b * R3V + v0 + lane];
    const float rc = 1.0f / fmaxf((float)cnt, 1.0f);
    const bool occ = cnt > 0;
    float* gb = grid + (size_t)b * 64 * R3V;
#pragma unroll
    for (int k = 0; k < 16; ++k) {
        const int c = w + k * 4;
        gb[(size_t)c * R3V + v0 + lane] = occ ? tile[lane][c] * rc : 0.0f;
    }
}

// ============================ fallback: LDS-atomic scatter ============================

__device__ __forceinline__ int swz(int v) {
    return v ^ ((v >> 5) & 31) ^ ((v >> 10) & 31);
}

__global__ void k_recip_fb(const int* __restrict__ cnt, float* __restrict__ recip, int total) {
    const int i = blockIdx.x * blockDim.x + threadIdx.x;
    if (i < total) recip[i] = 1.0f / fmaxf((float)cnt[i], 1.0f);
}

__global__ __launch_bounds__(1024, 1) void k_scatter_lds(
        const float* __restrict__ feats, const unsigned int* __restrict__ pk,
        const float* __restrict__ recip, float* __restrict__ grid, int N, int C) {
    extern __shared__ float acc[];
    const int bc  = blockIdx.x;
    const int b   = bc / C;
    const int tid = threadIdx.x;
    for (int i = tid * 4; i < R3V; i += blockDim.x * 4)
        *(float4*)(acc + i) = make_float4(0.f, 0.f, 0.f, 0.f);
    __syncthreads();
    const float* fb = feats + (size_t)bc * N;
    const unsigned int* ib = pk + (size_t)b * N;
    for (int n = tid; n < N; n += blockDim.x) atomicAdd(&acc[swz((int)(ib[n] >> 17))], fb[n]);
    __syncthreads();
    const float* rb = recip + (size_t)b * R3V;
    float*       gb = grid  + (size_t)bc * R3V;
    for (int i = tid; i < R3V; i += blockDim.x)
        gb[i] = acc[swz(i)] * rb[i];
}

// ============================ launch ============================

extern "C" void kernel_launch(void* const* d_in, const int* in_sizes, int n_in,
                              void* d_out, int out_size, void* d_ws, size_t ws_size,
                              hipStream_t stream) {
    const float* feats  = (const float*)d_in[0];
    const float* coords = (const float*)d_in[1];

    const long long s0 = in_sizes[0], s1 = in_sizes[1];
    const int BC = (int)(((long long)out_size - s1) / R3V);  // B*C
    const int N  = (int)(s0 / BC);
    const int B  = (int)(s1 / (3LL * N));
    const int C  = BC / B;

    float* out_grid = (float*)d_out;               // [B, C, R3]
    float* out_norm = out_grid + (size_t)BC * R3V; // [B, 3, N]

    // ws layout (float32 slots). Header = 1024 floats (sum + max partials).
    const size_t BR3 = (size_t)B * R3V;
    const size_t BN  = (size_t)B * N;
    const size_t o_counts = 1024;
    const size_t o_start  = o_counts + BR3;
    const size_t o_recip  = o_start + (size_t)B * R3P1;  // fallback only
    const size_t o_pk     = o_recip + BR3;
    const size_t o_voxid  = o_pk + BN;
    size_t o_gridT = (o_voxid + BN + 63) & ~(size_t)63;        // bf16: BR3*32 slots
    size_t o_fTs   = (o_gridT + BR3 * 32 + 63) & ~(size_t)63;  // bf16: BN*32 slots
    const size_t need = (o_fTs + BN * 32) * sizeof(float);

    float*        ws_part = (float*)d_ws;                  // [B*32*3]
    float*        ws_maxp = (float*)d_ws + 768;            // [B*32]
    int*          counts  = (int*)d_ws + o_counts;
    int*          startv  = (int*)d_ws + o_start;
    float*        recip   = (float*)d_ws + o_recip;
    unsigned int* pk      = (unsigned int*)d_ws + o_pk;
    int*          voxid   = (int*)d_ws + o_voxid;
    unsigned int* gridT2  = (unsigned int*)((float*)d_ws + o_gridT);
    unsigned int* fTs32   = (unsigned int*)((float*)d_ws + o_fTs);

    const int BLK = 256;
    dim3 gRed(32, B);
    // k_sums also zeroes counts (B*R3V ints == 256 blocks * 256 threads * int4)
    k_sums<<<gRed, BLK, 0, stream>>>(coords, ws_part, (int4*)counts, N);
    k_maxrad<<<gRed, BLK, 0, stream>>>(coords, ws_part, ws_maxp, N);

    dim3 gPts((N + BLK - 1) / BLK, B);
    k_points<<<gPts, BLK, 0, stream>>>(coords, ws_part, ws_maxp, out_norm, pk, counts, N);

    if (ws_size >= need && C == 64) {
        k_scan<<<dim3(B), 1024, 0, stream>>>(counts, startv, N);
        dim3 gT((N + 255) / 256, B);
        k_transpose_perm<<<gT, 1024, 0, stream>>>(feats, pk, startv, fTs32, voxid, N);
        const int nchunk = (N + CH - 1) / CH;
        dim3 gG((nchunk + 3) / 4, B);
        k_gather4<<<gG, 256, 0, stream>>>(fTs32, voxid, startv, gridT2, N, nchunk);
        dim3 gF(R3V / 64, B);
        k_fin<<<gF, 256, 0, stream>>>(gridT2, counts, out_grid);
    } else {
        const int tot = B * R3V;
        k_recip_fb<<<(tot + BLK - 1) / BLK, BLK, 0, stream>>>(counts, recip, tot);
        k_scatter_lds<<<dim3(BC), 1024, R3V * sizeof(float), stream>>>(
            feats, pk, recip, out_grid, N, C);
    }
}